// Round 4
// baseline (111.258 us; speedup 1.0000x reference)
//
#include <hip/hip_runtime.h>
#include <stdint.h>

#define K_   128
#define GD_  128
#define PSTR 20   // floats per (b,k) param record
#define KPW  32   // k's per wave (K_ / 4 waves)

typedef float v2f __attribute__((ext_vector_type(2)));

static __device__ __forceinline__ float fast_exp2(float x) {
#if __has_builtin(__builtin_amdgcn_exp2f)
    return __builtin_amdgcn_exp2f(x);
#else
    return exp2f(x);
#endif
}

// packed fma helpers: explicit llvm.fma.v2f32 -> v_pk_fma_f32 on gfx950
static __device__ __forceinline__ v2f vfma(v2f a, v2f b, v2f c) {
    return __builtin_elementwise_fma(a, b, c);
}
static __device__ __forceinline__ v2f vfma_s(float a, v2f b, v2f c) {
    return __builtin_elementwise_fma((v2f)(a), b, c);   // scalar splat in a
}

// ---------------- param kernel: one thread per (b,k) ----------------
//   G  = A_next * (R_next * R^T)            (3x3, grid-space transform)
//   v  = A_next * (c_next - R_rel*c) + t_next
//   q  = 2*s*log2e * c,  r = log2(c^2) - s*log2e*|c|^2,  s2n = -s*log2e
// Per point:  log2(w) = q.p + s2n*|p|^2 + r,  gridcoord = (Σw(G p + v))/Σw
// (world2grid + [-1,1] normalization + grid_sample denorm cancel exactly.)
__global__ void surf_param_kernel(
    const float* __restrict__ constants,
    const float* __restrict__ scales,
    const float* __restrict__ rotations,
    const float* __restrict__ centers,
    const float* __restrict__ w2g,
    float* __restrict__ params,
    float* __restrict__ out,
    int B)
{
    int idx = blockIdx.x * blockDim.x + threadIdx.x;
    if (idx == 0) out[0] = 0.0f;           // fused memset (runs before main kernel)
    if (idx >= B * K_) return;
    int b = idx / K_, k = idx - b * K_;
    int bn = (b + 1 == B) ? 0 : (b + 1);
    const float L2E = 1.4426950408889634f;

    const float* R  = rotations + (size_t)(b  * K_ + k) * 9;
    const float* Rt = rotations + (size_t)(bn * K_ + k) * 9;
    float m[9];
#pragma unroll
    for (int i = 0; i < 3; ++i)
#pragma unroll
        for (int l = 0; l < 3; ++l)
            m[i * 3 + l] = Rt[i * 3 + 0] * R[l * 3 + 0]
                         + Rt[i * 3 + 1] * R[l * 3 + 1]
                         + Rt[i * 3 + 2] * R[l * 3 + 2];

    const float* Aw = w2g + (size_t)bn * 16;   // rows [a0 a1 a2 t]
    float G[9], A[9] = {Aw[0], Aw[1], Aw[2], Aw[4], Aw[5], Aw[6], Aw[8], Aw[9], Aw[10]};
    float T[3] = {Aw[3], Aw[7], Aw[11]};
#pragma unroll
    for (int i = 0; i < 3; ++i)
#pragma unroll
        for (int l = 0; l < 3; ++l)
            G[i * 3 + l] = A[i * 3 + 0] * m[0 * 3 + l]
                         + A[i * 3 + 1] * m[1 * 3 + l]
                         + A[i * 3 + 2] * m[2 * 3 + l];

    const float* c  = centers + (size_t)(b  * K_ + k) * 3;
    const float* ct = centers + (size_t)(bn * K_ + k) * 3;
    float c0 = c[0], c1 = c[1], c2 = c[2];
    float vw0 = ct[0] - (m[0] * c0 + m[1] * c1 + m[2] * c2);
    float vw1 = ct[1] - (m[3] * c0 + m[4] * c1 + m[5] * c2);
    float vw2 = ct[2] - (m[6] * c0 + m[7] * c1 + m[8] * c2);
    float v0 = A[0] * vw0 + A[1] * vw1 + A[2] * vw2 + T[0];
    float v1 = A[3] * vw0 + A[4] * vw1 + A[5] * vw2 + T[1];
    float v2 = A[6] * vw0 + A[7] * vw1 + A[8] * vw2 + T[2];

    float sig = scales[b * K_ + k];
    float s   = 1.0f / (2.0f * sig * sig);
    float con = constants[b * K_ + k];
    float s2n = -s * L2E;
    float r   = log2f(con * con) + s2n * (c0 * c0 + c1 * c1 + c2 * c2);

    float* o = params + (size_t)idx * PSTR;
    o[0] = G[0]; o[1] = G[1]; o[2] = G[2]; o[3] = G[3];
    o[4] = G[4]; o[5] = G[5]; o[6] = G[6]; o[7] = G[7];
    o[8] = G[8]; o[9] = v0;  o[10] = v1;  o[11] = v2;
    o[12] = -2.0f * s2n * c0;
    o[13] = -2.0f * s2n * c1;
    o[14] = -2.0f * s2n * c2;
    o[15] = r;
    o[16] = s2n;
    o[17] = 0.f; o[18] = 0.f; o[19] = 0.f;
}

// ---------------- main kernel: K split across the block's 4 waves ----------------
// Block = 256 threads = 4 waves, handles 256 points of one batch (4/thread,
// held as 2 point-PAIRS in <2 x float> vectors). Wave w covers k in
// [32w,32w+32); partials combined through LDS; epilogue split by wave.
// Params arrive via the scalar pipe (k0 readfirstlane-uniform -> s_load,
// SGPR operands). Inner math is forced to v_pk_fma_f32 via
// __builtin_elementwise_fma on <2 x float> (R3's mul+add source may not
// have selected VOP3P) — 17 pk-FMA + 2 exp per point-pair per k.
__global__ __launch_bounds__(256) void surf_loss_kernel(
    const float* __restrict__ sp,      // (B,N,6)
    const float* __restrict__ grid,    // (B,GD,GD,GD)
    const float* __restrict__ params,  // (B,K,PSTR) precomputed
    float* __restrict__ out,
    int N, int B, int bpb)
{
    __shared__ float4 lds_part[4 * 4 * 64];    // 16 KB: [wave][j][lane]
    __shared__ float  red[4];

    const int tid  = threadIdx.x;
    const int lane = tid & 63;
    const int wave = tid >> 6;
    const int blk  = blockIdx.x;
    const int b    = blk / bpb;
    const int base = (blk - b * bpb) * 256;
    const int bn   = (b + 1 == B) ? 0 : (b + 1);

    // load this thread's 4 points as 2 pairs (same points in every wave/lane)
    v2f px2[2], py2[2], pz2[2], pq2[2];
    v2f ax2[2], ay2[2], az2[2], aw2[2];
    const float* spb = sp + (size_t)b * N * 6;
#pragma unroll
    for (int j = 0; j < 4; ++j) {
        int n = base + j * 64 + lane;
        int nn = (n < N) ? n : 0;
        const float* q = spb + (size_t)nn * 6;
        float x = q[0], y = q[1], z = q[2];
        px2[j >> 1][j & 1] = x;
        py2[j >> 1][j & 1] = y;
        pz2[j >> 1][j & 1] = z;
        pq2[j >> 1][j & 1] = x * x + y * y + z * z;
    }
#pragma unroll
    for (int g = 0; g < 2; ++g) {
        ax2[g] = (v2f)0.f; ay2[g] = (v2f)0.f; az2[g] = (v2f)0.f; aw2[g] = (v2f)0.f;
    }

    // wave-uniform k base, provably uniform to the compiler -> scalar loads
    const int k0 = __builtin_amdgcn_readfirstlane(wave * KPW);
    const float* __restrict__ pb = params + (size_t)b * K_ * PSTR + (size_t)k0 * PSTR;

    // K loop: this wave's 32 k's; params via scalar pipe, math via v_pk_fma_f32
#pragma unroll 2
    for (int kk = 0; kk < KPW; ++kk) {
        const float* pk = pb + kk * PSTR;
        const float4 f0 = *(const float4*)(pk + 0);   // G00 G01 G02 G10
        const float4 f1 = *(const float4*)(pk + 4);   // G11 G12 G20 G21
        const float4 f2 = *(const float4*)(pk + 8);   // G22 v0  v1  v2
        const float4 f3 = *(const float4*)(pk + 12);  // q0  q1  q2  r
        const float  s2 = pk[16];
#pragma unroll
        for (int g = 0; g < 2; ++g) {
            v2f e = vfma_s(s2, pq2[g],
                    vfma_s(f3.z, pz2[g],
                    vfma_s(f3.y, py2[g],
                    vfma_s(f3.x, px2[g], (v2f)(f3.w)))));
            v2f w2;
            w2.x = fast_exp2(e.x);
            w2.y = fast_exp2(e.y);
            v2f tx = vfma_s(f0.x, px2[g],
                     vfma_s(f0.y, py2[g],
                     vfma_s(f0.z, pz2[g], (v2f)(f2.y))));
            v2f ty = vfma_s(f0.w, px2[g],
                     vfma_s(f1.x, py2[g],
                     vfma_s(f1.y, pz2[g], (v2f)(f2.z))));
            v2f tz = vfma_s(f1.z, px2[g],
                     vfma_s(f1.w, py2[g],
                     vfma_s(f2.x, pz2[g], (v2f)(f2.w))));
            ax2[g] = vfma(w2, tx, ax2[g]);
            ay2[g] = vfma(w2, ty, ay2[g]);
            az2[g] = vfma(w2, tz, az2[g]);
            aw2[g] += w2;
        }
    }

    // write partials: [wave][j][lane]
#pragma unroll
    for (int j = 0; j < 4; ++j)
        lds_part[((wave * 4 + j) << 6) + lane] =
            make_float4(ax2[j >> 1][j & 1], ay2[j >> 1][j & 1],
                        az2[j >> 1][j & 1], aw2[j >> 1][j & 1]);
    __syncthreads();

    // epilogue: wave w takes point group j == wave
    float accum = 0.0f;
    {
        int n = base + wave * 64 + lane;
        if (n < N) {
            float sx = 0.f, sy = 0.f, sz = 0.f, sw = 0.f;
#pragma unroll
            for (int w = 0; w < 4; ++w) {
                float4 t = lds_part[((w * 4 + wave) << 6) + lane];
                sx += t.x; sy += t.y; sz += t.z; sw += t.w;
            }
            float inv = 1.0f / sw;
            float x = fminf(fmaxf(sx * inv, 0.0f), (float)(GD_ - 1));
            float y = fminf(fmaxf(sy * inv, 0.0f), (float)(GD_ - 1));
            float z = fminf(fmaxf(sz * inv, 0.0f), (float)(GD_ - 1));
            float x0f = floorf(x), y0f = floorf(y), z0f = floorf(z);
            float fx = x - x0f, fy = y - y0f, fz = z - z0f;
            int x0 = (int)x0f, y0 = (int)y0f, z0 = (int)z0f;
            int x1 = x0 + 1 > GD_ - 1 ? GD_ - 1 : x0 + 1;
            int y1 = y0 + 1 > GD_ - 1 ? GD_ - 1 : y0 + 1;
            int z1 = z0 + 1 > GD_ - 1 ? GD_ - 1 : z0 + 1;
            const float* gb = grid + (size_t)bn * GD_ * GD_ * GD_;
            int zy00 = (z0 * GD_ + y0) * GD_;
            int zy01 = (z0 * GD_ + y1) * GD_;
            int zy10 = (z1 * GD_ + y0) * GD_;
            int zy11 = (z1 * GD_ + y1) * GD_;
            float c000 = gb[zy00 + x0], c001 = gb[zy00 + x1];
            float c010 = gb[zy01 + x0], c011 = gb[zy01 + x1];
            float c100 = gb[zy10 + x0], c101 = gb[zy10 + x1];
            float c110 = gb[zy11 + x0], c111 = gb[zy11 + x1];
            float ofx = 1.0f - fx, ofy = 1.0f - fy, ofz = 1.0f - fz;
            float c00 = c000 * ofx + c001 * fx;
            float c01 = c010 * ofx + c011 * fx;
            float c10 = c100 * ofx + c101 * fx;
            float c11 = c110 * ofx + c111 * fx;
            float c0 = c00 * ofy + c01 * fy;
            float c1 = c10 * ofy + c11 * fy;
            float sdf = c0 * ofz + c1 * fz;
            accum = sdf * sdf;
        }
    }

    // per-wave shuffle reduce, then one atomic per block
#pragma unroll
    for (int off = 32; off > 0; off >>= 1)
        accum += __shfl_down(accum, off, 64);
    if (lane == 0) red[wave] = accum;
    __syncthreads();
    if (tid == 0)
        atomicAdd(out, (red[0] + red[1] + red[2] + red[3]) * (1.0f / (float)N));
}

extern "C" void kernel_launch(void* const* d_in, const int* in_sizes, int n_in,
                              void* d_out, int out_size, void* d_ws, size_t ws_size,
                              hipStream_t stream) {
    const float* constants = (const float*)d_in[0];
    const float* scales    = (const float*)d_in[1];
    const float* rotations = (const float*)d_in[2];
    const float* centers   = (const float*)d_in[3];
    const float* sp        = (const float*)d_in[4];
    const float* grid      = (const float*)d_in[5];
    const float* w2g       = (const float*)d_in[6];
    float* out = (float*)d_out;
    float* params = (float*)d_ws;            // B*K_*PSTR floats = 40 KB

    const int B = in_sizes[6] / 16;          // 4
    const int N = in_sizes[4] / (6 * B);     // 50000

    int np = B * K_;
    hipLaunchKernelGGL(surf_param_kernel, dim3((np + 255) / 256), dim3(256), 0, stream,
                       constants, scales, rotations, centers, w2g, params, out, B);

    const int bpb = (N + 255) / 256;         // blocks per batch (256 points/block)
    hipLaunchKernelGGL(surf_loss_kernel, dim3(B * bpb), dim3(256), 0, stream,
                       sp, grid, params, out, N, B, bpb);
}

// Round 5
// 108.029 us; speedup vs baseline: 1.0299x; 1.0299x over previous
//
#include <hip/hip_runtime.h>
#include <stdint.h>

#define K_   128
#define GD_  128
#define PSTR 20   // floats per (b,k) param record
#define KPW  32   // k's per wave (K_ / 4 waves)

typedef float v2f __attribute__((ext_vector_type(2)));

static __device__ __forceinline__ float fast_exp2(float x) {
#if __has_builtin(__builtin_amdgcn_exp2f)
    return __builtin_amdgcn_exp2f(x);
#else
    return exp2f(x);
#endif
}

// packed fma helpers: explicit llvm.fma.v2f32 -> v_pk_fma_f32 on gfx950
static __device__ __forceinline__ v2f vfma(v2f a, v2f b, v2f c) {
    return __builtin_elementwise_fma(a, b, c);
}
static __device__ __forceinline__ v2f vfma_s(float a, v2f b, v2f c) {
    return __builtin_elementwise_fma((v2f)(a), b, c);   // scalar splat in a
}

// ---------------- kernel 0: zero the output (1 thread, no loads) ----------------
// Replaces the old param kernel in the "zero before atomics" role with the
// cheapest possible dispatch: no memory reads -> no cold-HBM latency chain
// serializing the graph.
__global__ void zero_out_kernel(float* __restrict__ out) { out[0] = 0.0f; }

// ---------------- fused kernel ----------------
// Block = 256 threads = 4 waves, 256 points of one batch (4/thread, held as
// 2 point-pairs). Param records are computed IN-KERNEL: threads 0..127 each
// build record k=tid (G = A_next*R_next*R^T, v, q, r, s2n — world2grid +
// normalization + grid_sample denorm cancel exactly) straight into LDS,
// once per block, redundantly across blocks. This work (~150 VALU, tiny
// table loads that L2-hit after the first block) overlaps the point loads
// and is hidden by 784-block TLP — unlike the old 2-block param kernel,
// which sat latency-bound on cold HBM at the head of the graph.
// K-loop: wave w covers k in [32w,32w+32); params via LDS float4 broadcast
// reads (R2 measured DS-vs-scalar neutral); math is packed v_pk_fma_f32.
__global__ __launch_bounds__(256) void surf_fused_kernel(
    const float* __restrict__ constants,
    const float* __restrict__ scales,
    const float* __restrict__ rotations,
    const float* __restrict__ centers,
    const float* __restrict__ sp,      // (B,N,6)
    const float* __restrict__ grid,    // (B,GD,GD,GD)
    const float* __restrict__ w2g,     // (B,4,4)
    float* __restrict__ out,
    int N, int B, int bpb)
{
    __shared__ float  lds_par[K_ * PSTR];      // 10 KB param table
    __shared__ float4 lds_part[4 * 4 * 64];    // 16 KB: [wave][j][lane]
    __shared__ float  red[4];

    const int tid  = threadIdx.x;
    const int lane = tid & 63;
    const int wave = tid >> 6;
    const int blk  = blockIdx.x;
    const int b    = blk / bpb;
    const int base = (blk - b * bpb) * 256;
    const int bn   = (b + 1 == B) ? 0 : (b + 1);

    // issue this thread's 4 point loads first (overlap with param compute)
    v2f px2[2], py2[2], pz2[2], pq2[2];
    v2f ax2[2], ay2[2], az2[2], aw2[2];
    const float* spb = sp + (size_t)b * N * 6;
#pragma unroll
    for (int j = 0; j < 4; ++j) {
        int n = base + j * 64 + lane;
        int nn = (n < N) ? n : 0;
        const float* q = spb + (size_t)nn * 6;
        float x = q[0], y = q[1], z = q[2];
        px2[j >> 1][j & 1] = x;
        py2[j >> 1][j & 1] = y;
        pz2[j >> 1][j & 1] = z;
        pq2[j >> 1][j & 1] = x * x + y * y + z * z;
    }
#pragma unroll
    for (int g = 0; g < 2; ++g) {
        ax2[g] = (v2f)0.f; ay2[g] = (v2f)0.f; az2[g] = (v2f)0.f; aw2[g] = (v2f)0.f;
    }

    // ---- param phase: thread t (<128) computes record k=t into LDS ----
    if (tid < K_) {
        const int k = tid;
        const float L2E = 1.4426950408889634f;

        const float* R  = rotations + (size_t)(b  * K_ + k) * 9;
        const float* Rt = rotations + (size_t)(bn * K_ + k) * 9;
        float m[9];
#pragma unroll
        for (int i = 0; i < 3; ++i)
#pragma unroll
            for (int l = 0; l < 3; ++l)
                m[i * 3 + l] = Rt[i * 3 + 0] * R[l * 3 + 0]
                             + Rt[i * 3 + 1] * R[l * 3 + 1]
                             + Rt[i * 3 + 2] * R[l * 3 + 2];

        const float* Aw = w2g + (size_t)bn * 16;   // rows [a0 a1 a2 t]
        float G[9], A[9] = {Aw[0], Aw[1], Aw[2], Aw[4], Aw[5], Aw[6], Aw[8], Aw[9], Aw[10]};
        float T[3] = {Aw[3], Aw[7], Aw[11]};
#pragma unroll
        for (int i = 0; i < 3; ++i)
#pragma unroll
            for (int l = 0; l < 3; ++l)
                G[i * 3 + l] = A[i * 3 + 0] * m[0 * 3 + l]
                             + A[i * 3 + 1] * m[1 * 3 + l]
                             + A[i * 3 + 2] * m[2 * 3 + l];

        const float* c  = centers + (size_t)(b  * K_ + k) * 3;
        const float* ct = centers + (size_t)(bn * K_ + k) * 3;
        float c0 = c[0], c1 = c[1], c2 = c[2];
        float vw0 = ct[0] - (m[0] * c0 + m[1] * c1 + m[2] * c2);
        float vw1 = ct[1] - (m[3] * c0 + m[4] * c1 + m[5] * c2);
        float vw2 = ct[2] - (m[6] * c0 + m[7] * c1 + m[8] * c2);
        float v0 = A[0] * vw0 + A[1] * vw1 + A[2] * vw2 + T[0];
        float v1 = A[3] * vw0 + A[4] * vw1 + A[5] * vw2 + T[1];
        float v2 = A[6] * vw0 + A[7] * vw1 + A[8] * vw2 + T[2];

        float sig = scales[b * K_ + k];
        float s   = 1.0f / (2.0f * sig * sig);
        float con = constants[b * K_ + k];
        float s2n = -s * L2E;
        float r   = log2f(con * con) + s2n * (c0 * c0 + c1 * c1 + c2 * c2);

        float* o = lds_par + (size_t)k * PSTR;
        o[0] = G[0]; o[1] = G[1]; o[2] = G[2]; o[3] = G[3];
        o[4] = G[4]; o[5] = G[5]; o[6] = G[6]; o[7] = G[7];
        o[8] = G[8]; o[9] = v0;  o[10] = v1;  o[11] = v2;
        o[12] = -2.0f * s2n * c0;
        o[13] = -2.0f * s2n * c1;
        o[14] = -2.0f * s2n * c2;
        o[15] = r;
        o[16] = s2n;
        o[17] = 0.f; o[18] = 0.f; o[19] = 0.f;
    }
    __syncthreads();

    // ---- K loop: this wave's 32 k's; params via LDS broadcast float4 ----
    const int k0 = wave * KPW;
#pragma unroll 2
    for (int kk = 0; kk < KPW; ++kk) {
        const float4* f = (const float4*)(lds_par + (k0 + kk) * PSTR);
        const float4 f0 = f[0];   // G00 G01 G02 G10
        const float4 f1 = f[1];   // G11 G12 G20 G21
        const float4 f2 = f[2];   // G22 v0  v1  v2
        const float4 f3 = f[3];   // q0  q1  q2  r
        const float  s2 = lds_par[(k0 + kk) * PSTR + 16];
#pragma unroll
        for (int g = 0; g < 2; ++g) {
            v2f e = vfma_s(s2, pq2[g],
                    vfma_s(f3.z, pz2[g],
                    vfma_s(f3.y, py2[g],
                    vfma_s(f3.x, px2[g], (v2f)(f3.w)))));
            v2f w2;
            w2.x = fast_exp2(e.x);
            w2.y = fast_exp2(e.y);
            v2f tx = vfma_s(f0.x, px2[g],
                     vfma_s(f0.y, py2[g],
                     vfma_s(f0.z, pz2[g], (v2f)(f2.y))));
            v2f ty = vfma_s(f0.w, px2[g],
                     vfma_s(f1.x, py2[g],
                     vfma_s(f1.y, pz2[g], (v2f)(f2.z))));
            v2f tz = vfma_s(f1.z, px2[g],
                     vfma_s(f1.w, py2[g],
                     vfma_s(f2.x, pz2[g], (v2f)(f2.w))));
            ax2[g] = vfma(w2, tx, ax2[g]);
            ay2[g] = vfma(w2, ty, ay2[g]);
            az2[g] = vfma(w2, tz, az2[g]);
            aw2[g] += w2;
        }
    }

    // write partials: [wave][j][lane]
#pragma unroll
    for (int j = 0; j < 4; ++j)
        lds_part[((wave * 4 + j) << 6) + lane] =
            make_float4(ax2[j >> 1][j & 1], ay2[j >> 1][j & 1],
                        az2[j >> 1][j & 1], aw2[j >> 1][j & 1]);
    __syncthreads();

    // epilogue: wave w takes point group j == wave
    float accum = 0.0f;
    {
        int n = base + wave * 64 + lane;
        if (n < N) {
            float sx = 0.f, sy = 0.f, sz = 0.f, sw = 0.f;
#pragma unroll
            for (int w = 0; w < 4; ++w) {
                float4 t = lds_part[((w * 4 + wave) << 6) + lane];
                sx += t.x; sy += t.y; sz += t.z; sw += t.w;
            }
            float inv = 1.0f / sw;
            float x = fminf(fmaxf(sx * inv, 0.0f), (float)(GD_ - 1));
            float y = fminf(fmaxf(sy * inv, 0.0f), (float)(GD_ - 1));
            float z = fminf(fmaxf(sz * inv, 0.0f), (float)(GD_ - 1));
            float x0f = floorf(x), y0f = floorf(y), z0f = floorf(z);
            float fx = x - x0f, fy = y - y0f, fz = z - z0f;
            int x0 = (int)x0f, y0 = (int)y0f, z0 = (int)z0f;
            int x1 = x0 + 1 > GD_ - 1 ? GD_ - 1 : x0 + 1;
            int y1 = y0 + 1 > GD_ - 1 ? GD_ - 1 : y0 + 1;
            int z1 = z0 + 1 > GD_ - 1 ? GD_ - 1 : z0 + 1;
            const float* gb = grid + (size_t)bn * GD_ * GD_ * GD_;
            int zy00 = (z0 * GD_ + y0) * GD_;
            int zy01 = (z0 * GD_ + y1) * GD_;
            int zy10 = (z1 * GD_ + y0) * GD_;
            int zy11 = (z1 * GD_ + y1) * GD_;
            float c000 = gb[zy00 + x0], c001 = gb[zy00 + x1];
            float c010 = gb[zy01 + x0], c011 = gb[zy01 + x1];
            float c100 = gb[zy10 + x0], c101 = gb[zy10 + x1];
            float c110 = gb[zy11 + x0], c111 = gb[zy11 + x1];
            float ofx = 1.0f - fx, ofy = 1.0f - fy, ofz = 1.0f - fz;
            float c00 = c000 * ofx + c001 * fx;
            float c01 = c010 * ofx + c011 * fx;
            float c10 = c100 * ofx + c101 * fx;
            float c11 = c110 * ofx + c111 * fx;
            float c0 = c00 * ofy + c01 * fy;
            float c1 = c10 * ofy + c11 * fy;
            float sdf = c0 * ofz + c1 * fz;
            accum = sdf * sdf;
        }
    }

    // per-wave shuffle reduce, then one atomic per block
#pragma unroll
    for (int off = 32; off > 0; off >>= 1)
        accum += __shfl_down(accum, off, 64);
    if (lane == 0) red[wave] = accum;
    __syncthreads();
    if (tid == 0)
        atomicAdd(out, (red[0] + red[1] + red[2] + red[3]) * (1.0f / (float)N));
}

extern "C" void kernel_launch(void* const* d_in, const int* in_sizes, int n_in,
                              void* d_out, int out_size, void* d_ws, size_t ws_size,
                              hipStream_t stream) {
    const float* constants = (const float*)d_in[0];
    const float* scales    = (const float*)d_in[1];
    const float* rotations = (const float*)d_in[2];
    const float* centers   = (const float*)d_in[3];
    const float* sp        = (const float*)d_in[4];
    const float* grid      = (const float*)d_in[5];
    const float* w2g       = (const float*)d_in[6];
    float* out = (float*)d_out;

    const int B = in_sizes[6] / 16;          // 4
    const int N = in_sizes[4] / (6 * B);     // 50000

    hipLaunchKernelGGL(zero_out_kernel, dim3(1), dim3(1), 0, stream, out);

    const int bpb = (N + 255) / 256;         // blocks per batch (256 points/block)
    hipLaunchKernelGGL(surf_fused_kernel, dim3(B * bpb), dim3(256), 0, stream,
                       constants, scales, rotations, centers, sp, grid, w2g,
                       out, N, B, bpb);
}

// Round 7
// 105.305 us; speedup vs baseline: 1.0565x; 1.0259x over previous
//
#include <hip/hip_runtime.h>
#include <stdint.h>

#define K_   128
#define GD_  128
#define PSTR 20   // floats per (b,k) param record
#define KPW  32   // k's per wave (K_ / 4 waves)

typedef float v2f __attribute__((ext_vector_type(2)));

static __device__ __forceinline__ float fast_exp2(float x) {
#if __has_builtin(__builtin_amdgcn_exp2f)
    return __builtin_amdgcn_exp2f(x);
#else
    return exp2f(x);
#endif
}

// packed fma helpers: explicit llvm.fma.v2f32 -> v_pk_fma_f32 on gfx950
static __device__ __forceinline__ v2f vfma(v2f a, v2f b, v2f c) {
    return __builtin_elementwise_fma(a, b, c);
}
static __device__ __forceinline__ v2f vfma_s(float a, v2f b, v2f c) {
    return __builtin_elementwise_fma((v2f)(a), b, c);   // scalar splat in a
}

// ---------------- kernel 0: zero the output (1 thread, no loads) ----------------
// Cheapest possible "zero before atomics" dispatch: no memory reads -> no
// cold-HBM latency chain serializing the graph. (R6 showed the cooperative
// single-dispatch replacement fails to launch under graph capture.)
__global__ void zero_out_kernel(float* __restrict__ out) { out[0] = 0.0f; }

// ---------------- fused kernel ----------------
// Block = 256 threads = 4 waves, 256 points of one batch (4/thread, held as
// 2 point-pairs). Param records are computed IN-KERNEL: threads 0..127 each
// build record k=tid (G = A_next*R_next*R^T, v, q, r, s2n — world2grid +
// normalization + grid_sample denorm cancel exactly) straight into LDS,
// once per block, redundantly across blocks. This work overlaps the point
// loads and is hidden by 784-block TLP — measured worth ~3 µs vs the old
// separate param kernel (cold-HBM latency-bound at the head of the graph).
// K-loop: wave w covers k in [32w,32w+32); params via LDS float4 broadcast
// reads (R2: DS vs scalar-pipe neutral); math is packed v_pk_fma_f32
// (R3/R4: issue-count sweep neutral -> k-loop not binding).
__global__ __launch_bounds__(256) void surf_fused_kernel(
    const float* __restrict__ constants,
    const float* __restrict__ scales,
    const float* __restrict__ rotations,
    const float* __restrict__ centers,
    const float* __restrict__ sp,      // (B,N,6)
    const float* __restrict__ grid,    // (B,GD,GD,GD)
    const float* __restrict__ w2g,     // (B,4,4)
    float* __restrict__ out,
    int N, int B, int bpb)
{
    __shared__ float  lds_par[K_ * PSTR];      // 10 KB param table
    __shared__ float4 lds_part[4 * 4 * 64];    // 16 KB: [wave][j][lane]
    __shared__ float  red[4];

    const int tid  = threadIdx.x;
    const int lane = tid & 63;
    const int wave = tid >> 6;
    const int blk  = blockIdx.x;
    const int b    = blk / bpb;
    const int base = (blk - b * bpb) * 256;
    const int bn   = (b + 1 == B) ? 0 : (b + 1);

    // issue this thread's 4 point loads first (overlap with param compute)
    v2f px2[2], py2[2], pz2[2], pq2[2];
    v2f ax2[2], ay2[2], az2[2], aw2[2];
    const float* spb = sp + (size_t)b * N * 6;
#pragma unroll
    for (int j = 0; j < 4; ++j) {
        int n = base + j * 64 + lane;
        int nn = (n < N) ? n : 0;
        const float* q = spb + (size_t)nn * 6;
        float x = q[0], y = q[1], z = q[2];
        px2[j >> 1][j & 1] = x;
        py2[j >> 1][j & 1] = y;
        pz2[j >> 1][j & 1] = z;
        pq2[j >> 1][j & 1] = x * x + y * y + z * z;
    }
#pragma unroll
    for (int g = 0; g < 2; ++g) {
        ax2[g] = (v2f)0.f; ay2[g] = (v2f)0.f; az2[g] = (v2f)0.f; aw2[g] = (v2f)0.f;
    }

    // ---- param phase: thread t (<128) computes record k=t into LDS ----
    if (tid < K_) {
        const int k = tid;
        const float L2E = 1.4426950408889634f;

        const float* R  = rotations + (size_t)(b  * K_ + k) * 9;
        const float* Rt = rotations + (size_t)(bn * K_ + k) * 9;
        float m[9];
#pragma unroll
        for (int i = 0; i < 3; ++i)
#pragma unroll
            for (int l = 0; l < 3; ++l)
                m[i * 3 + l] = Rt[i * 3 + 0] * R[l * 3 + 0]
                             + Rt[i * 3 + 1] * R[l * 3 + 1]
                             + Rt[i * 3 + 2] * R[l * 3 + 2];

        const float* Aw = w2g + (size_t)bn * 16;   // rows [a0 a1 a2 t]
        float G[9], A[9] = {Aw[0], Aw[1], Aw[2], Aw[4], Aw[5], Aw[6], Aw[8], Aw[9], Aw[10]};
        float T[3] = {Aw[3], Aw[7], Aw[11]};
#pragma unroll
        for (int i = 0; i < 3; ++i)
#pragma unroll
            for (int l = 0; l < 3; ++l)
                G[i * 3 + l] = A[i * 3 + 0] * m[0 * 3 + l]
                             + A[i * 3 + 1] * m[1 * 3 + l]
                             + A[i * 3 + 2] * m[2 * 3 + l];

        const float* c  = centers + (size_t)(b  * K_ + k) * 3;
        const float* ct = centers + (size_t)(bn * K_ + k) * 3;
        float c0 = c[0], c1 = c[1], c2 = c[2];
        float vw0 = ct[0] - (m[0] * c0 + m[1] * c1 + m[2] * c2);
        float vw1 = ct[1] - (m[3] * c0 + m[4] * c1 + m[5] * c2);
        float vw2 = ct[2] - (m[6] * c0 + m[7] * c1 + m[8] * c2);
        float v0 = A[0] * vw0 + A[1] * vw1 + A[2] * vw2 + T[0];
        float v1 = A[3] * vw0 + A[4] * vw1 + A[5] * vw2 + T[1];
        float v2 = A[6] * vw0 + A[7] * vw1 + A[8] * vw2 + T[2];

        float sig = scales[b * K_ + k];
        float s   = 1.0f / (2.0f * sig * sig);
        float con = constants[b * K_ + k];
        float s2n = -s * L2E;
        float r   = log2f(con * con) + s2n * (c0 * c0 + c1 * c1 + c2 * c2);

        float* o = lds_par + (size_t)k * PSTR;
        o[0] = G[0]; o[1] = G[1]; o[2] = G[2]; o[3] = G[3];
        o[4] = G[4]; o[5] = G[5]; o[6] = G[6]; o[7] = G[7];
        o[8] = G[8]; o[9] = v0;  o[10] = v1;  o[11] = v2;
        o[12] = -2.0f * s2n * c0;
        o[13] = -2.0f * s2n * c1;
        o[14] = -2.0f * s2n * c2;
        o[15] = r;
        o[16] = s2n;
        o[17] = 0.f; o[18] = 0.f; o[19] = 0.f;
    }
    __syncthreads();

    // ---- K loop: this wave's 32 k's; params via LDS broadcast float4 ----
    const int k0 = wave * KPW;
#pragma unroll 2
    for (int kk = 0; kk < KPW; ++kk) {
        const float4* f = (const float4*)(lds_par + (k0 + kk) * PSTR);
        const float4 f0 = f[0];   // G00 G01 G02 G10
        const float4 f1 = f[1];   // G11 G12 G20 G21
        const float4 f2 = f[2];   // G22 v0  v1  v2
        const float4 f3 = f[3];   // q0  q1  q2  r
        const float  s2 = lds_par[(k0 + kk) * PSTR + 16];
#pragma unroll
        for (int g = 0; g < 2; ++g) {
            v2f e = vfma_s(s2, pq2[g],
                    vfma_s(f3.z, pz2[g],
                    vfma_s(f3.y, py2[g],
                    vfma_s(f3.x, px2[g], (v2f)(f3.w)))));
            v2f w2;
            w2.x = fast_exp2(e.x);
            w2.y = fast_exp2(e.y);
            v2f tx = vfma_s(f0.x, px2[g],
                     vfma_s(f0.y, py2[g],
                     vfma_s(f0.z, pz2[g], (v2f)(f2.y))));
            v2f ty = vfma_s(f0.w, px2[g],
                     vfma_s(f1.x, py2[g],
                     vfma_s(f1.y, pz2[g], (v2f)(f2.z))));
            v2f tz = vfma_s(f1.z, px2[g],
                     vfma_s(f1.w, py2[g],
                     vfma_s(f2.x, pz2[g], (v2f)(f2.w))));
            ax2[g] = vfma(w2, tx, ax2[g]);
            ay2[g] = vfma(w2, ty, ay2[g]);
            az2[g] = vfma(w2, tz, az2[g]);
            aw2[g] += w2;
        }
    }

    // write partials: [wave][j][lane]
#pragma unroll
    for (int j = 0; j < 4; ++j)
        lds_part[((wave * 4 + j) << 6) + lane] =
            make_float4(ax2[j >> 1][j & 1], ay2[j >> 1][j & 1],
                        az2[j >> 1][j & 1], aw2[j >> 1][j & 1]);
    __syncthreads();

    // epilogue: wave w takes point group j == wave
    float accum = 0.0f;
    {
        int n = base + wave * 64 + lane;
        if (n < N) {
            float sx = 0.f, sy = 0.f, sz = 0.f, sw = 0.f;
#pragma unroll
            for (int w = 0; w < 4; ++w) {
                float4 t = lds_part[((w * 4 + wave) << 6) + lane];
                sx += t.x; sy += t.y; sz += t.z; sw += t.w;
            }
            float inv = 1.0f / sw;
            float x = fminf(fmaxf(sx * inv, 0.0f), (float)(GD_ - 1));
            float y = fminf(fmaxf(sy * inv, 0.0f), (float)(GD_ - 1));
            float z = fminf(fmaxf(sz * inv, 0.0f), (float)(GD_ - 1));
            float x0f = floorf(x), y0f = floorf(y), z0f = floorf(z);
            float fx = x - x0f, fy = y - y0f, fz = z - z0f;
            int x0 = (int)x0f, y0 = (int)y0f, z0 = (int)z0f;
            int x1 = x0 + 1 > GD_ - 1 ? GD_ - 1 : x0 + 1;
            int y1 = y0 + 1 > GD_ - 1 ? GD_ - 1 : y0 + 1;
            int z1 = z0 + 1 > GD_ - 1 ? GD_ - 1 : z0 + 1;
            const float* gb = grid + (size_t)bn * GD_ * GD_ * GD_;
            int zy00 = (z0 * GD_ + y0) * GD_;
            int zy01 = (z0 * GD_ + y1) * GD_;
            int zy10 = (z1 * GD_ + y0) * GD_;
            int zy11 = (z1 * GD_ + y1) * GD_;
            float c000 = gb[zy00 + x0], c001 = gb[zy00 + x1];
            float c010 = gb[zy01 + x0], c011 = gb[zy01 + x1];
            float c100 = gb[zy10 + x0], c101 = gb[zy10 + x1];
            float c110 = gb[zy11 + x0], c111 = gb[zy11 + x1];
            float ofx = 1.0f - fx, ofy = 1.0f - fy, ofz = 1.0f - fz;
            float c00 = c000 * ofx + c001 * fx;
            float c01 = c010 * ofx + c011 * fx;
            float c10 = c100 * ofx + c101 * fx;
            float c11 = c110 * ofx + c111 * fx;
            float c0 = c00 * ofy + c01 * fy;
            float c1 = c10 * ofy + c11 * fy;
            float sdf = c0 * ofz + c1 * fz;
            accum = sdf * sdf;
        }
    }

    // per-wave shuffle reduce, then one atomic per block
#pragma unroll
    for (int off = 32; off > 0; off >>= 1)
        accum += __shfl_down(accum, off, 64);
    if (lane == 0) red[wave] = accum;
    __syncthreads();
    if (tid == 0)
        atomicAdd(out, (red[0] + red[1] + red[2] + red[3]) * (1.0f / (float)N));
}

extern "C" void kernel_launch(void* const* d_in, const int* in_sizes, int n_in,
                              void* d_out, int out_size, void* d_ws, size_t ws_size,
                              hipStream_t stream) {
    const float* constants = (const float*)d_in[0];
    const float* scales    = (const float*)d_in[1];
    const float* rotations = (const float*)d_in[2];
    const float* centers   = (const float*)d_in[3];
    const float* sp        = (const float*)d_in[4];
    const float* grid      = (const float*)d_in[5];
    const float* w2g       = (const float*)d_in[6];
    float* out = (float*)d_out;

    const int B = in_sizes[6] / 16;          // 4
    const int N = in_sizes[4] / (6 * B);     // 50000

    hipLaunchKernelGGL(zero_out_kernel, dim3(1), dim3(1), 0, stream, out);

    const int bpb = (N + 255) / 256;         // blocks per batch (256 points/block)
    hipLaunchKernelGGL(surf_fused_kernel, dim3(B * bpb), dim3(256), 0, stream,
                       constants, scales, rotations, centers, sp, grid, w2g,
                       out, N, B, bpb);
}